// Round 4
// baseline (1612.304 us; speedup 1.0000x reference)
//
#include <hip/hip_runtime.h>
#include <math.h>

#define Bc 256
#define Tc 1024
#define RNN_DIMc 1024
#define ENC_DIMc 512
#define ATT_DIMc 128
#define NFILTc 32
#define KSIZEc 31
#define PADc 15
#define CHTc 128                 // ctx chunk rows
#define NCHc 8                   // chunks per b
#define N_ENERGY Bc              // 256 energy tasks
#define NTASKS (N_ENERGY + Bc * NCHc)   // 256 + 2048
#define FLAG_STRIDE 16           // pad flags to 64B lines

typedef float f4v __attribute__((ext_vector_type(4)));

__device__ __forceinline__ float fast_tanh(float x) {
    x = fminf(15.f, fmaxf(-15.f, x));
    float z = __expf(2.f * x);
    return (z - 1.f) / (z + 1.f);
}

__device__ __forceinline__ float wave_reduce_max(float x) {
#pragma unroll
    for (int off = 32; off > 0; off >>= 1) x = fmaxf(x, __shfl_xor(x, off, 64));
    return x;
}

__device__ __forceinline__ float wave_reduce_sum(float x) {
#pragma unroll
    for (int off = 32; off > 0; off >>= 1) x += __shfl_xor(x, off, 64);
    return x;
}

// zero flags/done/counter (workspace is poisoned each iteration)
__global__ __launch_bounds__(256) void init_k(int* __restrict__ ctrl) {
    ctrl[blockIdx.x * 256 + threadIdx.x] = 0;
}

// Persistent work-queue kernel: energy tasks + context-chunk tasks in one launch.
__global__ __launch_bounds__(256, 4) void lsa_persist(
    const float* __restrict__ query, const float* __restrict__ memory,
    const float* __restrict__ pm, const float* __restrict__ attn_w,
    const float* __restrict__ cum_w, const int* __restrict__ lens,
    const float* __restrict__ conv_w, const float* __restrict__ W_loc,
    const float* __restrict__ W_q, const float* __restrict__ v_w,
    const float* __restrict__ v_b, int* __restrict__ ctrl,
    float* __restrict__ part, float* __restrict__ ctx,
    float* __restrict__ out_attn, float* __restrict__ out_cum) {

    __shared__ float s_q[RNN_DIMc];              // 4 KiB
    __shared__ float s_pq[ATT_DIMc];
    __shared__ float s_pqh[ATT_DIMc];
    __shared__ float s_win0[Tc + 2 * PADc];      // 4.2 KiB
    __shared__ float s_win1[Tc + 2 * PADc];      // 4.2 KiB
    __shared__ float s_e[Tc];                    // 4 KiB
    __shared__ float s_red[4];
    __shared__ float s_red2[4];
    __shared__ float s_w[CHTc];
    __shared__ float s_part[4][ENC_DIMc];        // 8 KiB
    __shared__ int s_task;
    __shared__ int s_old;

    const int tid = threadIdx.x;
    int* flags   = ctrl;                         // Bc * FLAG_STRIDE ints
    int* done    = ctrl + Bc * FLAG_STRIDE;      // Bc ints
    int* counter = done + Bc;                    // 1 int

    while (true) {
        __syncthreads();                         // protect LDS + s_task reuse
        if (tid == 0) s_task = atomicAdd(counter, 1);
        __syncthreads();
        const int task = s_task;
        if (task >= NTASKS) return;

        if (task < N_ENERGY) {
            // ================= ENERGY TASK: one b, 256 threads x 4 t each =================
            const int b = task;
            const int len = lens[b];
            {
                const int i4 = tid * 4;
                *(f4v*)&s_q[i4] = *(const f4v*)&query[(size_t)b * RNN_DIMc + i4];
            }
            for (int i = tid; i < Tc + 2 * PADc; i += 256) {
                int tt = i - PADc;
                bool ok = (tt >= 0) && (tt < Tc);
                s_win0[i] = ok ? attn_w[b * Tc + tt] : 0.f;
                s_win1[i] = ok ? cum_w[b * Tc + tt] : 0.f;
            }
            __syncthreads();
            // pq: 2 threads per a-row, 512 r each
            {
                const int a = tid & 127;
                const int h = tid >> 7;
                const float* w = W_q + (size_t)a * RNN_DIMc + h * 512;
                const float* qq = s_q + h * 512;
                float acc = 0.f;
#pragma unroll 4
                for (int r = 0; r < 512; r += 4) {
                    float4 wv = *(const float4*)(w + r);
                    acc = fmaf(wv.x, qq[r + 0], acc);
                    acc = fmaf(wv.y, qq[r + 1], acc);
                    acc = fmaf(wv.z, qq[r + 2], acc);
                    acc = fmaf(wv.w, qq[r + 3], acc);
                }
                if (h) s_pqh[a] = acc; else s_pq[a] = acc;
            }
            __syncthreads();
            if (tid < ATT_DIMc) s_pq[tid] += s_pqh[tid];
            __syncthreads();

            // energies: 4 sub-chunks, e -> s_e (LDS; avoids per-thread dyn-indexed array)
            for (int sct = 0; sct < 4; ++sct) {
                const int t = (sct << 8) + tid;
                float e = -INFINITY;
                if (t < len) {
                    float loc[NFILTc];
#pragma unroll
                    for (int f = 0; f < NFILTc; ++f) loc[f] = 0.f;
                    for (int k = 0; k < KSIZEc; ++k) {
                        const float wa = s_win0[t + k];
                        const float wc = s_win1[t + k];
#pragma unroll
                        for (int f = 0; f < NFILTc; ++f) {
                            loc[f] = fmaf(conv_w[f * (2 * KSIZEc) + k], wa, loc[f]);
                            loc[f] = fmaf(conv_w[f * (2 * KSIZEc) + KSIZEc + k], wc, loc[f]);
                        }
                    }
                    const float* pmrow = pm + ((size_t)(b * Tc + t)) * ATT_DIMc;
                    float acc = 0.f;
#pragma unroll 2
                    for (int a = 0; a < ATT_DIMc; a += 4) {
                        const f4v pmv = __builtin_nontemporal_load((const f4v*)(pmrow + a));
                        const float* wl = W_loc + a * NFILTc;
                        float pl0 = 0.f, pl1 = 0.f, pl2 = 0.f, pl3 = 0.f;
#pragma unroll
                        for (int f = 0; f < NFILTc; ++f) {
                            float lf = loc[f];
                            pl0 = fmaf(wl[f], lf, pl0);
                            pl1 = fmaf(wl[NFILTc + f], lf, pl1);
                            pl2 = fmaf(wl[2 * NFILTc + f], lf, pl2);
                            pl3 = fmaf(wl[3 * NFILTc + f], lf, pl3);
                        }
                        acc = fmaf(v_w[a + 0], fast_tanh(s_pq[a + 0] + pl0 + pmv.x), acc);
                        acc = fmaf(v_w[a + 1], fast_tanh(s_pq[a + 1] + pl1 + pmv.y), acc);
                        acc = fmaf(v_w[a + 2], fast_tanh(s_pq[a + 2] + pl2 + pmv.z), acc);
                        acc = fmaf(v_w[a + 3], fast_tanh(s_pq[a + 3] + pl3 + pmv.w), acc);
                    }
                    e = acc + v_b[0];
                }
                s_e[t] = e;
            }
            __syncthreads();
            // softmax over 1024 entries
            {
                float m4 = fmaxf(fmaxf(s_e[tid], s_e[tid + 256]),
                                 fmaxf(s_e[tid + 512], s_e[tid + 768]));
                float m = wave_reduce_max(m4);
                if ((tid & 63) == 0) s_red[tid >> 6] = m;
                __syncthreads();
                const float bm = fmaxf(fmaxf(s_red[0], s_red[1]), fmaxf(s_red[2], s_red[3]));
                float psum = 0.f;
#pragma unroll
                for (int sct = 0; sct < 4; ++sct) {
                    const int t = (sct << 8) + tid;
                    float p = __expf(s_e[t] - bm);   // exp(-inf)=0 for masked
                    s_e[t] = p;
                    psum += p;
                }
                float sw = wave_reduce_sum(psum);
                if ((tid & 63) == 0) s_red2[tid >> 6] = sw;
                __syncthreads();
                const float inv = 1.f / (s_red2[0] + s_red2[1] + s_red2[2] + s_red2[3]);
#pragma unroll
                for (int sct = 0; sct < 4; ++sct) {
                    const int t = (sct << 8) + tid;
                    const float na = s_e[t] * inv;
                    out_attn[b * Tc + t] = na;
                    out_cum[b * Tc + t] = s_win1[t + PADc] + na;
                }
            }
            __syncthreads();  // all attn stores complete (vmcnt drained) before release
            if (tid == 0)
                __hip_atomic_store(&flags[b * FLAG_STRIDE], 1,
                                   __ATOMIC_RELEASE, __HIP_MEMORY_SCOPE_AGENT);
        } else {
            // ================= CTX CHUNK TASK: 128 rows of memory[b] =================
            const int idx = task - N_ENERGY;
            const int b = idx & (Bc - 1);     // round-robin over b
            const int ch = idx >> 8;          // 0..7
            const int t0 = ch * CHTc;
            const int len = lens[b];
            if (t0 < len) {
                if (tid == 0) {
                    while (__hip_atomic_load(&flags[b * FLAG_STRIDE],
                                             __ATOMIC_ACQUIRE, __HIP_MEMORY_SCOPE_AGENT) == 0)
                        __builtin_amdgcn_s_sleep(8);
                }
                __syncthreads();
                int lim = len - t0;
                if (lim > CHTc) lim = CHTc;
                if (tid < CHTc) s_w[tid] = out_attn[b * Tc + t0 + tid];
                __syncthreads();

                const int tr = tid >> 6;          // 0..3 wave id = t-residue
                const int e8 = (tid & 63) * 8;    // 0..504
                const float* mb = memory + ((size_t)(b * Tc + t0)) * ENC_DIMc;
                f4v acc0 = {0.f, 0.f, 0.f, 0.f};
                f4v acc1 = {0.f, 0.f, 0.f, 0.f};
#pragma unroll 4
                for (int tt = tr; tt < lim; tt += 4) {
                    const float wgt = s_w[tt];    // wave-uniform broadcast
                    const float* row = mb + (size_t)tt * ENC_DIMc + e8;
                    const f4v m0 = __builtin_nontemporal_load((const f4v*)(row));
                    const f4v m1 = __builtin_nontemporal_load((const f4v*)(row + 4));
                    acc0.x = fmaf(wgt, m0.x, acc0.x);
                    acc0.y = fmaf(wgt, m0.y, acc0.y);
                    acc0.z = fmaf(wgt, m0.z, acc0.z);
                    acc0.w = fmaf(wgt, m0.w, acc0.w);
                    acc1.x = fmaf(wgt, m1.x, acc1.x);
                    acc1.y = fmaf(wgt, m1.y, acc1.y);
                    acc1.z = fmaf(wgt, m1.z, acc1.z);
                    acc1.w = fmaf(wgt, m1.w, acc1.w);
                }
                *(f4v*)&s_part[tr][e8] = acc0;
                *(f4v*)&s_part[tr][e8 + 4] = acc1;
                __syncthreads();
                const size_t pbase = (size_t)(b * NCHc + ch) * ENC_DIMc;
                for (int c = tid; c < ENC_DIMc; c += 256)
                    part[pbase + c] = s_part[0][c] + s_part[1][c] + s_part[2][c] + s_part[3][c];
                __syncthreads();  // partial stores drained before signaling done
                if (tid == 0)
                    s_old = __hip_atomic_fetch_add(&done[b], 1,
                                                   __ATOMIC_ACQ_REL, __HIP_MEMORY_SCOPE_AGENT);
                __syncthreads();
                const int nact = (len + CHTc - 1) >> 7;   // active chunks for this b
                if (s_old == nact - 1) {
                    // last finisher: deterministic reduce over chunk partials
                    const float* pb = part + (size_t)b * NCHc * ENC_DIMc;
                    for (int c = tid; c < ENC_DIMc; c += 256) {
                        float sfin = 0.f;
                        for (int c2 = 0; c2 < nact; ++c2)
                            sfin += pb[(size_t)c2 * ENC_DIMc + c];
                        ctx[b * ENC_DIMc + c] = sfin;
                    }
                }
            }
        }
    }
}

extern "C" void kernel_launch(void* const* d_in, const int* in_sizes, int n_in,
                              void* d_out, int out_size, void* d_ws, size_t ws_size,
                              hipStream_t stream) {
    const float* query  = (const float*)d_in[0];
    const float* memory = (const float*)d_in[1];
    const float* pm     = (const float*)d_in[2];
    const float* attn_w = (const float*)d_in[3];
    const float* cum_w  = (const float*)d_in[4];
    const int*   lens   = (const int*)d_in[5];
    const float* conv_w = (const float*)d_in[6];
    const float* W_loc  = (const float*)d_in[7];
    const float* W_q    = (const float*)d_in[8];
    const float* v_w    = (const float*)d_in[9];
    const float* v_b    = (const float*)d_in[10];

    float* out      = (float*)d_out;
    float* ctx      = out;                              // B*ENC_DIM
    float* out_attn = out + Bc * ENC_DIMc;              // B*T
    float* out_cum  = out + Bc * ENC_DIMc + Bc * Tc;    // B*T

    // workspace: [ctrl: flags(256*16) + done(256) + counter(1) ints][pad][part: 4 MB]
    int*   ctrl = (int*)d_ws;
    float* part = (float*)d_ws + 8192;                  // 32 KB offset

    init_k<<<18, 256, 0, stream>>>(ctrl);               // zeroes 4608 ints >= 4353 used
    lsa_persist<<<1024, 256, 0, stream>>>(query, memory, pm, attn_w, cum_w, lens,
                                          conv_w, W_loc, W_q, v_w, v_b,
                                          ctrl, part, ctx, out_attn, out_cum);
}